// Round 5
// baseline (165.603 us; speedup 1.0000x reference)
//
#include <hip/hip_runtime.h>
#include <stdint.h>

typedef unsigned int u32;
typedef unsigned long long u64;

#define HW (1024*1024)
#define NSLICE 16
#define BATCH 8
#define KTOP 500
#define CAP 8192u
#define LCAP 256u
#define POST_MAX 83
#define DELTA_THR 9728u     // v > 1 - 9728*2^-24 ~ 0.99942; E[count/slice] ~ 580

// workspace byte offsets
#define WS_CNT   0          // u32[16*16]  one counter per 64B line per slice
#define WS_FLAG  1024       // u32[16]
#define WS_DONE  1088       // u32[16]
#define WS_HIST  2048       // u32[16*256] -> ends 18432
#define WS_CAND  32768      // uint2[16*8192] -> ends 1081344
#define WS_S1    1081344    // uint2[16*512] -> ends 1146880
#define WS_ADJ   1146880    // u64[8*4096] = 256 KiB -> ends 1409024
#define WS_ORDV  1409024    // u32[8*512] -> ends 1425408

// out layout (floats): boxes[0,36000) scores[36000,40000) clses[40000,44000)
// valid[44000,48000) keep[48000,52000)

// ---------------- K1: streaming collect, block-aggregated atomics ------------
__global__ __launch_bounds__(256) void k1_collect(const float* __restrict__ heat,
                                                  u32* cnt, u32* flag, u32* done,
                                                  uint2* cand){
  __shared__ uint2 lbuf[LCAP];
  __shared__ u32 lcnt, gbase;
  int s     = blockIdx.x >> 7;   // 16 slices x 128 chunks
  int chunk = blockIdx.x & 127;
  int tid   = threadIdx.x;
  if (tid == 0) lcnt = 0;
  __syncthreads();
  const float4* hp = (const float4*)(heat + (size_t)s*HW + (size_t)chunk*8192);
  u32 base_pos = (u32)chunk * 8192u;
  for (int it = 0; it < 8; ++it){
    float4 v = hp[it*256 + tid];
    u32 idx0 = base_pos + (u32)(it*256 + tid)*4u;
    #pragma unroll
    for (int c = 0; c < 4; ++c){
      float val = (c==0)?v.x:(c==1)?v.y:(c==2)?v.z:v.w;
      u32 bits  = __float_as_uint(val);
      u32 delta = 0x3F800000u - bits;         // ulps below 1.0
      if (delta < DELTA_THR){
        u32 p = atomicAdd(&lcnt, 1u);         // LDS atomic, rare (~5/block)
        if (p < LCAP) lbuf[p] = make_uint2(bits, idx0 + (u32)c);
        else {                                // overflow: direct global (never on this data)
          u32 gp = atomicAdd(&cnt[s*16], 1u);
          if (gp < CAP) cand[(size_t)s*CAP + gp] = make_uint2(bits, idx0 + (u32)c);
        }
      }
    }
  }
  __syncthreads();
  u32 n = (lcnt < LCAP) ? lcnt : LCAP;
  if (tid == 0) gbase = atomicAdd(&cnt[s*16], n);   // ONE global atomic per block
  __syncthreads();
  for (u32 i = tid; i < n; i += 256){
    u32 p = gbase + i;
    if (p < CAP) cand[(size_t)s*CAP + p] = lbuf[i];
  }
  __syncthreads();
  if (tid == 0){
    __threadfence();
    u32 d = atomicAdd(&done[s], 1u);
    if (d == 127u){                            // last block of slice
      u32 c = atomicAdd(&cnt[s*16], 0u);       // coherent read
      if (c >= (u32)KTOP) flag[s] = 1u;
      else { flag[s] = 0u; cnt[s*16] = 0u; }   // fallback recollects
    }
  }
}

// ---------------- K_hist: fallback histogram (early-exit normally) -----------
__global__ __launch_bounds__(256) void k_hist(const float* __restrict__ heat,
                                              const u32* __restrict__ flag, u32* ghist){
  int s = blockIdx.x >> 4;       // 16 slices x 16 chunks
  if (flag[s]) return;
  int chunk = blockIdx.x & 15;
  int tid = threadIdx.x;
  __shared__ u32 lhist[256];
  lhist[tid] = 0;
  __syncthreads();
  const float4* hp = (const float4*)(heat + (size_t)s*HW + (size_t)chunk*65536);
  for (int it = 0; it < 64; ++it){
    float4 v = hp[it*256 + tid];
    #pragma unroll
    for (int c = 0; c < 4; ++c){
      float val = (c==0)?v.x:(c==1)?v.y:(c==2)?v.z:v.w;
      u32 bits  = __float_as_uint(val);
      u32 delta = 0x3F800000u - bits;
      u32 bin   = delta >> 16; if (bin > 255u) bin = 255u;
      atomicAdd(&lhist[bin], 1u);
    }
  }
  __syncthreads();
  atomicAdd(&ghist[s*256 + tid], lhist[tid]);
}

// ---------------- K3: fallback exact collect (early-exit normally) -----------
__global__ __launch_bounds__(256) void k3_fallback(const float* __restrict__ heat,
                                                   u32* cnt, const u32* __restrict__ flag,
                                                   const u32* __restrict__ ghist, uint2* cand){
  int s = blockIdx.x >> 4;
  if (flag[s]) return;
  int chunk = blockIdx.x & 15;
  int tid = threadIdx.x;
  __shared__ int t2s;
  if (tid == 0){
    u32 cum = 0; u32 b1 = 255u;
    for (u32 bb = 0; bb < 256u; ++bb){
      cum += ghist[s*256 + (int)bb];
      if (cum >= (u32)KTOP){ b1 = bb; break; }
    }
    t2s = (int)(0x3F800000u - ((b1 + 1u) << 16) + 1u);
  }
  __syncthreads();
  int t2 = t2s;
  const float4* hp = (const float4*)(heat + (size_t)s*HW + (size_t)chunk*65536);
  u32 base_pos = (u32)chunk * 65536u;
  for (int it = 0; it < 64; ++it){
    float4 v = hp[it*256 + tid];
    u32 idx0 = base_pos + (u32)(it*256 + tid)*4u;
    #pragma unroll
    for (int c = 0; c < 4; ++c){
      float val = (c==0)?v.x:(c==1)?v.y:(c==2)?v.z:v.w;
      int bits = (int)__float_as_uint(val);   // signed cmp excludes negatives
      if (bits >= t2){
        u32 pos = atomicAdd(&cnt[s*16], 1u);
        if (pos < CAP) cand[(size_t)s*CAP + pos] = make_uint2((u32)bits, idx0 + (u32)c);
      }
    }
  }
}

// ---------------- bitonic sort (ascending, u64 keys in LDS) -----------------
__device__ inline void bitonic_sort(u64* key, int N, int tid, int nthr){
  for (int len = 2; len <= N; len <<= 1){
    for (int stride = len >> 1; stride > 0; stride >>= 1){
      __syncthreads();
      for (int i = tid; i < N; i += nthr){
        int j = i ^ stride;
        if (j > i){
          u64 a = key[i], b = key[j];
          bool up = ((i & len) == 0);
          if ((a > b) == up){ key[i] = b; key[j] = a; }
        }
      }
    }
  }
  __syncthreads();
}

// ---------------- KA: per-slice exact top-500 --------------------------------
__global__ __launch_bounds__(1024) void kA_sort(const u32* __restrict__ cnt,
                                                const uint2* __restrict__ cand, uint2* s1){
  __shared__ u64 key[8192];   // 64 KiB (large NP only on fallback path)
  int s = blockIdx.x, tid = threadIdx.x;
  u32 n = cnt[s*16]; if (n > CAP) n = CAP;
  int NP = 1024; while (NP < (int)n) NP <<= 1;
  for (int i = tid; i < NP; i += 1024){
    u64 k = ~0ull;
    if (i < (int)n){
      uint2 cv = cand[(size_t)s*CAP + i];
      k = ((u64)(~cv.x) << 32) | (u64)cv.y;   // value desc, index asc
    }
    key[i] = k;
  }
  bitonic_sort(key, NP, tid, 1024);
  if (tid < KTOP){
    u64 k = key[tid];
    s1[s*512 + tid] = make_uint2(~(u32)(k >> 32), (u32)(k & 0xFFFFFFFFull));
  }
}

// ---------------- KB1: merge + decode + partition + adjacency ---------------
__global__ __launch_bounds__(1024) void kB1_prep(const uint2* __restrict__ s1,
                                                 const float* __restrict__ reg,
                                                 const float* __restrict__ rots,
                                                 const float* __restrict__ rotc,
                                                 const float* __restrict__ hei,
                                                 const float* __restrict__ dim,
                                                 const float* __restrict__ vel,
                                                 float* out, u64* adjg, u32* ordv){
  __shared__ u64 key[1024];
  __shared__ uint2 topv[2][512];
  __shared__ float xo[512], yo[512], xs_s[512], ys_s[512];
  __shared__ int order[512], vld[512];
  __shared__ int wsum[16];
  int b = blockIdx.x, t = threadIdx.x;

  // ---- load both sorted 500-lists
  if (t < 512) topv[0][t]     = s1[(b*2 + 0)*512 + t];
  else         topv[1][t-512] = s1[(b*2 + 1)*512 + (t-512)];
  __syncthreads();

  // ---- 10-pass bitonic merge (list0 asc, list1 desc; tie-break = c*K pos)
  {
    u64 k;
    if (t < 512){
      k = (t < KTOP) ? (((u64)(~topv[0][t].x) << 32) | (u64)t) : ~0ull;
    } else {
      int p = 511 - (t - 512);
      k = (p < KTOP) ? (((u64)(~topv[1][p].x) << 32) | (u64)(KTOP + p)) : ~0ull;
    }
    key[t] = k;
  }
  for (int stride = 512; stride > 0; stride >>= 1){
    __syncthreads();
    int j = t ^ stride;
    if (j > t){
      u64 a = key[t], bb = key[j];
      if (a > bb){ key[t] = bb; key[j] = a; }
    }
  }
  __syncthreads();

  u32 myind = 0; float mysc = 0.0f;
  if (t < KTOP){
    u64 k = key[t];
    u32 src = (u32)k;                 // position in concatenated c*K array
    int c = (src >= (u32)KTOP) ? 1 : 0;
    int pos = (int)src - c*KTOP;
    myind = topv[c][pos].y;
    mysc = __uint_as_float(~(u32)(k >> 32));
    out[36000 + b*KTOP + t] = mysc;
    out[40000 + b*KTOP + t] = (float)c;
  }

  // ---- gather + decode + valid
  float x = 0.f, y = 0.f; int v = 0;
  if (t < KTOP){
    u32 ind = myind & (u32)(HW - 1);
    float xs0 = (float)(ind & 1023u);
    float ys0 = (float)(ind >> 10);
    size_t bb = (size_t)b;
    float r0  = reg [(bb*2 + 0)*HW + ind];
    float r1  = reg [(bb*2 + 1)*HW + ind];
    float sn  = rots[ bb       *HW + ind];
    float cs  = rotc[ bb       *HW + ind];
    float he  = hei [ bb       *HW + ind];
    float d0  = dim [(bb*3 + 0)*HW + ind];
    float d1  = dim [(bb*3 + 1)*HW + ind];
    float d2v = dim [(bb*3 + 2)*HW + ind];
    float v0  = vel [(bb*2 + 0)*HW + ind];
    float v1  = vel [(bb*2 + 1)*HW + ind];
    x = xs0 + r0; y = ys0 + r1;
    float rot = atan2f(sn, cs);
    float* bx = out + (size_t)(b*KTOP + t)*9;
    bx[0]=x; bx[1]=y; bx[2]=he; bx[3]=d0; bx[4]=d1; bx[5]=d2v; bx[6]=rot; bx[7]=v0; bx[8]=v1;
    v = ((x >= -100.0f) && (x <= 1124.0f) &&
         (y >= -100.0f) && (y <= 1124.0f) &&
         (he >= -10.0f) && (he <= 10.0f) && (mysc > 0.1f)) ? 1 : 0;
    out[44000 + b*KTOP + t] = v ? 1.0f : 0.0f;
  }
  if (t < 512){ xo[t] = x; yo[t] = y; vld[t] = v; }

  // ---- 1-barrier ballot scan: stable valid-first partition
  u64 bm = __ballot(v != 0);
  int lane = t & 63, wv = t >> 6;
  if (lane == 0) wsum[wv] = __popcll(bm);
  __syncthreads();
  int off = 0, nValid = 0;
  #pragma unroll
  for (int w2 = 0; w2 < 8; ++w2){
    int sv = wsum[w2];
    nValid += sv;
    if (w2 < wv) off += sv;
  }
  int incl = off + __popcll(bm & ((~0ull) >> (63 - lane)));
  if (t < KTOP){
    int excl = incl - v;
    int slot = v ? excl : (nValid + (t - excl));
    order[slot] = t;
  }
  __syncthreads();
  if (t < KTOP){
    int p = order[t];
    xs_s[t] = xo[p]; ys_s[t] = yo[p];
    ordv[b*512 + t] = (u32)p | ((u32)vld[p] << 31);
  }
  __syncthreads();

  // ---- adjacency bitmask rows (16 waves) -> global ws
  int wv6 = t >> 6, ln = t & 63;
  u64* ag = adjg + (size_t)b*4096;
  for (int i = wv6; i < KTOP; i += 16){
    float xi = xs_s[i], yi = ys_s[i];
    #pragma unroll
    for (int jc = 0; jc < 8; ++jc){
      int j = jc*64 + ln;
      bool pred = false;
      if (j < KTOP && j > i){
        float dx = __fsub_rn(xs_s[j], xi);
        float dy = __fsub_rn(ys_s[j], yi);
        float d2 = __fadd_rn(__fmul_rn(dx,dx), __fmul_rn(dy,dy));
        pred = (d2 <= 4.0f);
      }
      u64 m = __ballot(pred);
      if (ln == 0) ag[i*8 + jc] = m;
    }
  }
}

// ---------------- KB2: greedy suppression + cap + keep-write -----------------
__global__ __launch_bounds__(256) void kB2_greedy(const u64* __restrict__ adjg,
                                                  const u32* __restrict__ ordv,
                                                  float* out){
  __shared__ u64 adjL[4000];   // 31.25 KiB
  __shared__ u64 keepw[8];
  int b = blockIdx.x, t = threadIdx.x;
  const u64* src = adjg + (size_t)b*4096;
  for (int i = t; i < 4000; i += 256) adjL[i] = src[i];
  __syncthreads();

  // one wave; lanes 0..7 own 64-bit supp words; readlane broadcast of bit i
  if (t < 64){
    int ln8 = t & 7;
    u64 supp = 0ull;
    u64 row = adjL[ln8];                       // row 0 prefetched
    for (int i = 0; i < KTOP; ++i){
      u64 rown = adjL[(i+1 < KTOP ? i+1 : i)*8 + ln8];   // prefetch next
      u32 lo = (u32)supp, hi = (u32)(supp >> 32);
      u32 sel = (i & 32) ? hi : lo;
      u32 wbit = (u32)__builtin_amdgcn_readlane((int)sel, i >> 6);  // uniform lane
      if (!((wbit >> (i & 31)) & 1u)) supp |= row;       // wave-uniform branch
      row = rown;
    }
    if (t < 8){
      u64 kp = ~supp;
      if (t == 7) kp &= ((1ull << 52) - 1ull);  // j in [448,500)
      keepw[t] = kp;
    }
  }
  __syncthreads();

  // cumsum cap at POST_MAX
  if (t == 0){
    int budget = POST_MAX;
    for (int c2 = 0; c2 < 8; ++c2){
      u64 w = keepw[c2];
      int n = __popcll(w);
      if (n <= budget){ budget -= n; }
      else {
        while (n > budget){ w &= ~(1ull << (63 - __clzll(w))); --n; }
        budget = 0;
      }
      keepw[c2] = w;
    }
  }
  __syncthreads();
  for (int e = t; e < KTOP; e += 256){
    int bit = (int)((keepw[e >> 6] >> (e & 63)) & 1ull);
    u32 pv = ordv[b*512 + e];
    int p = (int)(pv & 511u);
    out[48000 + b*KTOP + p] = (bit && (pv >> 31)) ? 1.0f : 0.0f;
  }
}

extern "C" void kernel_launch(void* const* d_in, const int* in_sizes, int n_in,
                              void* d_out, int out_size, void* d_ws, size_t ws_size,
                              hipStream_t stream){
  const float* heat = (const float*)d_in[0];
  const float* reg  = (const float*)d_in[1];
  const float* rots = (const float*)d_in[2];
  const float* rotc = (const float*)d_in[3];
  const float* hei  = (const float*)d_in[4];
  const float* dim  = (const float*)d_in[5];
  const float* vel  = (const float*)d_in[6];
  float* out = (float*)d_out;
  char* ws = (char*)d_ws;
  u32*   cnt   = (u32*)  (ws + WS_CNT);
  u32*   flag  = (u32*)  (ws + WS_FLAG);
  u32*   done  = (u32*)  (ws + WS_DONE);
  u32*   ghist = (u32*)  (ws + WS_HIST);
  uint2* cand  = (uint2*)(ws + WS_CAND);
  uint2* s1    = (uint2*)(ws + WS_S1);
  u64*   adjg  = (u64*)  (ws + WS_ADJ);
  u32*   ordv  = (u32*)  (ws + WS_ORDV);

  hipMemsetAsync(ws, 0, 18432, stream);   // cnt + flag + done + hist
  k1_collect <<<2048, 256, 0, stream>>>(heat, cnt, flag, done, cand);
  k_hist     <<<256,  256, 0, stream>>>(heat, flag, ghist);
  k3_fallback<<<256,  256, 0, stream>>>(heat, cnt, flag, ghist, cand);
  kA_sort    <<<16,  1024, 0, stream>>>(cnt, cand, s1);
  kB1_prep   <<<8,   1024, 0, stream>>>(s1, reg, rots, rotc, hei, dim, vel, out, adjg, ordv);
  kB2_greedy <<<8,    256, 0, stream>>>(adjg, ordv, out);
}

// Round 6
// 125.770 us; speedup vs baseline: 1.3167x; 1.3167x over previous
//
#include <hip/hip_runtime.h>
#include <stdint.h>

typedef unsigned int u32;
typedef unsigned long long u64;

#define HW (1024*1024)
#define NSLICE 16
#define BATCH 8
#define KTOP 500
#define CAP 8192u
#define LCAP 256u
#define POST_MAX 83
#define DELTA_THR 9728u     // v > 1 - 9728*2^-24 ~ 0.99942; E[count/slice] ~ 580

// workspace byte offsets
#define WS_CNT   0          // u32[16*16]  one counter per 64B line per slice
#define WS_CAND  32768      // uint2[16*8192] -> ends 1081344
#define WS_S1    1081344    // uint2[16*512] -> ends 1146880
#define WS_ADJ   1146880    // u64[8*4096] = 256 KiB -> ends 1409024
#define WS_ORDV  1409024    // u32[8*512] -> ends 1425408

// out layout (floats): boxes[0,36000) scores[36000,40000) clses[40000,44000)
// valid[44000,48000) keep[48000,52000)

// ---------------- K1: streaming collect, batched loads, no fences ------------
__global__ __launch_bounds__(256) void k1_collect(const float* __restrict__ heat,
                                                  u32* cnt, uint2* cand){
  __shared__ uint2 lbuf[LCAP];
  __shared__ u32 lcnt, gbase;
  int s     = blockIdx.x >> 7;   // 16 slices x 128 chunks
  int chunk = blockIdx.x & 127;
  int tid   = threadIdx.x;
  if (tid == 0) lcnt = 0;
  __syncthreads();
  const float4* hp = (const float4*)(heat + (size_t)s*HW + (size_t)chunk*8192);
  // issue all 8 loads back-to-back: 8 KB/wave in flight
  float4 v[8];
  #pragma unroll
  for (int i = 0; i < 8; ++i) v[i] = hp[i*256 + tid];
  #pragma unroll
  for (int i = 0; i < 8; ++i){
    u32 idx0 = (u32)chunk*8192u + (u32)(i*256 + tid)*4u;
    float vals[4] = {v[i].x, v[i].y, v[i].z, v[i].w};
    #pragma unroll
    for (int c = 0; c < 4; ++c){
      u32 bits  = __float_as_uint(vals[c]);
      u32 delta = 0x3F800000u - bits;         // ulps below 1.0
      if (delta < DELTA_THR){
        u32 p = atomicAdd(&lcnt, 1u);         // LDS atomic, rare (~5/block)
        if (p < LCAP) lbuf[p] = make_uint2(bits, idx0 + (u32)c);
        else {                                // overflow: direct global (never on this data)
          u32 gp = atomicAdd(&cnt[s*16], 1u);
          if (gp < CAP) cand[(size_t)s*CAP + gp] = make_uint2(bits, idx0 + (u32)c);
        }
      }
    }
  }
  __syncthreads();
  u32 n = (lcnt < LCAP) ? lcnt : LCAP;
  if (tid == 0) gbase = atomicAdd(&cnt[s*16], n);   // ONE global atomic per block
  __syncthreads();
  for (u32 i = tid; i < n; i += 256){
    u32 p = gbase + i;
    if (p < CAP) cand[(size_t)s*CAP + p] = lbuf[i];
  }
  // no fence, no done-flag: kernel boundary is the release point
}

// ---------------- bitonic sort (ascending, u64 keys in LDS) -----------------
__device__ inline void bitonic_sort(u64* key, int N, int tid, int nthr){
  for (int len = 2; len <= N; len <<= 1){
    for (int stride = len >> 1; stride > 0; stride >>= 1){
      __syncthreads();
      for (int i = tid; i < N; i += nthr){
        int j = i ^ stride;
        if (j > i){
          u64 a = key[i], b = key[j];
          bool up = ((i & len) == 0);
          if ((a > b) == up){ key[i] = b; key[j] = a; }
        }
      }
    }
  }
  __syncthreads();
}

// ---------------- KA: per-slice exact top-500 (self-contained fallback) ------
__global__ __launch_bounds__(1024) void kA_sort(const float* __restrict__ heat,
                                                const u32* __restrict__ cnt,
                                                uint2* cand, uint2* s1){
  __shared__ u64 key[8192];   // 64 KiB (large NP only on fallback path)
  __shared__ u32 lhist[256];
  __shared__ u32 lc;
  __shared__ int t2s;
  int s = blockIdx.x, tid = threadIdx.x;
  u32 n = cnt[s*16]; if (n > CAP) n = CAP;

  if (n < (u32)KTOP){
    // ---- exactness fallback (never taken on this data): hist + recollect ----
    for (int i = tid; i < 256; i += 1024) lhist[i] = 0;
    if (tid == 0) lc = 0;
    __syncthreads();
    const float4* hp = (const float4*)(heat + (size_t)s*HW);
    for (int it = 0; it < 256; ++it){
      float4 v = hp[it*1024 + tid];
      #pragma unroll
      for (int c = 0; c < 4; ++c){
        float val = (c==0)?v.x:(c==1)?v.y:(c==2)?v.z:v.w;
        u32 bits  = __float_as_uint(val);
        u32 delta = 0x3F800000u - bits;
        u32 bin   = delta >> 16; if (bin > 255u) bin = 255u;
        atomicAdd(&lhist[bin], 1u);
      }
    }
    __syncthreads();
    if (tid == 0){
      u32 cum = 0; u32 b1 = 255u;
      for (u32 bb = 0; bb < 256u; ++bb){
        cum += lhist[bb];
        if (cum >= (u32)KTOP){ b1 = bb; break; }
      }
      t2s = (int)(0x3F800000u - ((b1 + 1u) << 16) + 1u);
    }
    __syncthreads();
    int t2 = t2s;
    for (int it = 0; it < 256; ++it){
      float4 v = hp[it*1024 + tid];
      u32 idx0 = (u32)(it*1024 + tid)*4u;
      #pragma unroll
      for (int c = 0; c < 4; ++c){
        float val = (c==0)?v.x:(c==1)?v.y:(c==2)?v.z:v.w;
        int bits = (int)__float_as_uint(val);   // signed cmp excludes negatives
        if (bits >= t2){
          u32 p = atomicAdd(&lc, 1u);
          if (p < CAP) cand[(size_t)s*CAP + p] = make_uint2((u32)bits, idx0 + (u32)c);
        }
      }
    }
    __syncthreads();
    n = (lc < CAP) ? lc : CAP;
  }

  int NP = 1024; while (NP < (int)n) NP <<= 1;
  for (int i = tid; i < NP; i += 1024){
    u64 k = ~0ull;
    if (i < (int)n){
      uint2 cv = cand[(size_t)s*CAP + i];
      k = ((u64)(~cv.x) << 32) | (u64)cv.y;   // value desc, index asc
    }
    key[i] = k;
  }
  bitonic_sort(key, NP, tid, 1024);
  if (tid < KTOP){
    u64 k = key[tid];
    s1[s*512 + tid] = make_uint2(~(u32)(k >> 32), (u32)(k & 0xFFFFFFFFull));
  }
}

// ---------------- KB1: merge + decode + partition + adjacency ---------------
__global__ __launch_bounds__(1024) void kB1_prep(const uint2* __restrict__ s1,
                                                 const float* __restrict__ reg,
                                                 const float* __restrict__ rots,
                                                 const float* __restrict__ rotc,
                                                 const float* __restrict__ hei,
                                                 const float* __restrict__ dim,
                                                 const float* __restrict__ vel,
                                                 float* out, u64* adjg, u32* ordv){
  __shared__ u64 key[1024];
  __shared__ uint2 topv[2][512];
  __shared__ float xo[512], yo[512], xs_s[512], ys_s[512];
  __shared__ int order[512], vld[512];
  __shared__ int wsum[16];
  int b = blockIdx.x, t = threadIdx.x;

  // ---- load both sorted 500-lists
  if (t < 512) topv[0][t]     = s1[(b*2 + 0)*512 + t];
  else         topv[1][t-512] = s1[(b*2 + 1)*512 + (t-512)];
  __syncthreads();

  // ---- 10-pass bitonic merge (list0 asc, list1 desc; tie-break = c*K pos)
  {
    u64 k;
    if (t < 512){
      k = (t < KTOP) ? (((u64)(~topv[0][t].x) << 32) | (u64)t) : ~0ull;
    } else {
      int p = 511 - (t - 512);
      k = (p < KTOP) ? (((u64)(~topv[1][p].x) << 32) | (u64)(KTOP + p)) : ~0ull;
    }
    key[t] = k;
  }
  for (int stride = 512; stride > 0; stride >>= 1){
    __syncthreads();
    int j = t ^ stride;
    if (j > t){
      u64 a = key[t], bb = key[j];
      if (a > bb){ key[t] = bb; key[j] = a; }
    }
  }
  __syncthreads();

  u32 myind = 0; float mysc = 0.0f;
  if (t < KTOP){
    u64 k = key[t];
    u32 src = (u32)k;                 // position in concatenated c*K array
    int c = (src >= (u32)KTOP) ? 1 : 0;
    int pos = (int)src - c*KTOP;
    myind = topv[c][pos].y;
    mysc = __uint_as_float(~(u32)(k >> 32));
    out[36000 + b*KTOP + t] = mysc;
    out[40000 + b*KTOP + t] = (float)c;
  }

  // ---- gather + decode + valid
  float x = 0.f, y = 0.f; int v = 0;
  if (t < KTOP){
    u32 ind = myind & (u32)(HW - 1);
    float xs0 = (float)(ind & 1023u);
    float ys0 = (float)(ind >> 10);
    size_t bb = (size_t)b;
    float r0  = reg [(bb*2 + 0)*HW + ind];
    float r1  = reg [(bb*2 + 1)*HW + ind];
    float sn  = rots[ bb       *HW + ind];
    float cs  = rotc[ bb       *HW + ind];
    float he  = hei [ bb       *HW + ind];
    float d0  = dim [(bb*3 + 0)*HW + ind];
    float d1  = dim [(bb*3 + 1)*HW + ind];
    float d2v = dim [(bb*3 + 2)*HW + ind];
    float v0  = vel [(bb*2 + 0)*HW + ind];
    float v1  = vel [(bb*2 + 1)*HW + ind];
    x = xs0 + r0; y = ys0 + r1;
    float rot = atan2f(sn, cs);
    float* bx = out + (size_t)(b*KTOP + t)*9;
    bx[0]=x; bx[1]=y; bx[2]=he; bx[3]=d0; bx[4]=d1; bx[5]=d2v; bx[6]=rot; bx[7]=v0; bx[8]=v1;
    v = ((x >= -100.0f) && (x <= 1124.0f) &&
         (y >= -100.0f) && (y <= 1124.0f) &&
         (he >= -10.0f) && (he <= 10.0f) && (mysc > 0.1f)) ? 1 : 0;
    out[44000 + b*KTOP + t] = v ? 1.0f : 0.0f;
  }
  if (t < 512){ xo[t] = x; yo[t] = y; vld[t] = v; }

  // ---- 1-barrier ballot scan: stable valid-first partition
  u64 bm = __ballot(v != 0);
  int lane = t & 63, wv = t >> 6;
  if (lane == 0) wsum[wv] = __popcll(bm);
  __syncthreads();
  int off = 0, nValid = 0;
  #pragma unroll
  for (int w2 = 0; w2 < 8; ++w2){
    int sv = wsum[w2];
    nValid += sv;
    if (w2 < wv) off += sv;
  }
  int incl = off + __popcll(bm & ((~0ull) >> (63 - lane)));
  if (t < KTOP){
    int excl = incl - v;
    int slot = v ? excl : (nValid + (t - excl));
    order[slot] = t;
  }
  __syncthreads();
  if (t < KTOP){
    int p = order[t];
    xs_s[t] = xo[p]; ys_s[t] = yo[p];
    ordv[b*512 + t] = (u32)p | ((u32)vld[p] << 31);
  }
  __syncthreads();

  // ---- adjacency bitmask rows (16 waves) -> global ws
  int wv6 = t >> 6, ln = t & 63;
  u64* ag = adjg + (size_t)b*4096;
  for (int i = wv6; i < KTOP; i += 16){
    float xi = xs_s[i], yi = ys_s[i];
    #pragma unroll
    for (int jc = 0; jc < 8; ++jc){
      int j = jc*64 + ln;
      bool pred = false;
      if (j < KTOP && j > i){
        float dx = __fsub_rn(xs_s[j], xi);
        float dy = __fsub_rn(ys_s[j], yi);
        float d2 = __fadd_rn(__fmul_rn(dx,dx), __fmul_rn(dy,dy));
        pred = (d2 <= 4.0f);
      }
      u64 m = __ballot(pred);
      if (ln == 0) ag[i*8 + jc] = m;
    }
  }
}

// ---------------- KB2: greedy suppression + cap + keep-write -----------------
__global__ __launch_bounds__(256) void kB2_greedy(const u64* __restrict__ adjg,
                                                  const u32* __restrict__ ordv,
                                                  float* out){
  __shared__ u64 adjL[4000];   // 31.25 KiB
  __shared__ u64 keepw[8];
  int b = blockIdx.x, t = threadIdx.x;
  const u64* src = adjg + (size_t)b*4096;
  for (int i = t; i < 4000; i += 256) adjL[i] = src[i];
  __syncthreads();

  // one wave; lanes 0..7 own 64-bit supp words; readlane broadcast of bit i
  if (t < 64){
    int ln8 = t & 7;
    u64 supp = 0ull;
    u64 row = adjL[ln8];                       // row 0 prefetched
    for (int i = 0; i < KTOP; ++i){
      u64 rown = adjL[(i+1 < KTOP ? i+1 : i)*8 + ln8];   // prefetch next
      u32 lo = (u32)supp, hi = (u32)(supp >> 32);
      u32 sel = (i & 32) ? hi : lo;
      u32 wbit = (u32)__builtin_amdgcn_readlane((int)sel, i >> 6);  // uniform lane
      if (!((wbit >> (i & 31)) & 1u)) supp |= row;       // wave-uniform branch
      row = rown;
    }
    if (t < 8){
      u64 kp = ~supp;
      if (t == 7) kp &= ((1ull << 52) - 1ull);  // j in [448,500)
      keepw[t] = kp;
    }
  }
  __syncthreads();

  // cumsum cap at POST_MAX
  if (t == 0){
    int budget = POST_MAX;
    for (int c2 = 0; c2 < 8; ++c2){
      u64 w = keepw[c2];
      int n = __popcll(w);
      if (n <= budget){ budget -= n; }
      else {
        while (n > budget){ w &= ~(1ull << (63 - __clzll(w))); --n; }
        budget = 0;
      }
      keepw[c2] = w;
    }
  }
  __syncthreads();
  for (int e = t; e < KTOP; e += 256){
    int bit = (int)((keepw[e >> 6] >> (e & 63)) & 1ull);
    u32 pv = ordv[b*512 + e];
    int p = (int)(pv & 511u);
    out[48000 + b*KTOP + p] = (bit && (pv >> 31)) ? 1.0f : 0.0f;
  }
}

extern "C" void kernel_launch(void* const* d_in, const int* in_sizes, int n_in,
                              void* d_out, int out_size, void* d_ws, size_t ws_size,
                              hipStream_t stream){
  const float* heat = (const float*)d_in[0];
  const float* reg  = (const float*)d_in[1];
  const float* rots = (const float*)d_in[2];
  const float* rotc = (const float*)d_in[3];
  const float* hei  = (const float*)d_in[4];
  const float* dim  = (const float*)d_in[5];
  const float* vel  = (const float*)d_in[6];
  float* out = (float*)d_out;
  char* ws = (char*)d_ws;
  u32*   cnt   = (u32*)  (ws + WS_CNT);
  uint2* cand  = (uint2*)(ws + WS_CAND);
  uint2* s1    = (uint2*)(ws + WS_S1);
  u64*   adjg  = (u64*)  (ws + WS_ADJ);
  u32*   ordv  = (u32*)  (ws + WS_ORDV);

  hipMemsetAsync(ws, 0, 1024, stream);    // cnt only
  k1_collect <<<2048, 256, 0, stream>>>(heat, cnt, cand);
  kA_sort    <<<16,  1024, 0, stream>>>(heat, cnt, cand, s1);
  kB1_prep   <<<8,   1024, 0, stream>>>(s1, reg, rots, rotc, hei, dim, vel, out, adjg, ordv);
  kB2_greedy <<<8,    256, 0, stream>>>(adjg, ordv, out);
}

// Round 7
// 123.493 us; speedup vs baseline: 1.3410x; 1.0184x over previous
//
#include <hip/hip_runtime.h>
#include <stdint.h>

typedef unsigned int u32;
typedef unsigned long long u64;

#define HW (1024*1024)
#define NSLICE 16
#define BATCH 8
#define KTOP 500
#define CAP 8192u
#define CAP2 4096u
#define LCAP 256u
#define POST_MAX 83
#define DELTA_THR 9728u     // v > 1 - 9728*2^-24 ~ 0.99942; E[count/slice] ~ 580

// workspace byte offsets
#define WS_CNT   0          // u32[16*16]  one counter per 64B line per slice
#define WS_CAND  32768      // uint2[16*8192] -> ends 1081344

// out layout (floats): boxes[0,36000) scores[36000,40000) clses[40000,44000)
// valid[44000,48000) keep[48000,52000)

// ---------------- K1: streaming collect, batched loads, no fences ------------
__global__ __launch_bounds__(256) void k1_collect(const float* __restrict__ heat,
                                                  u32* cnt, uint2* cand){
  __shared__ uint2 lbuf[LCAP];
  __shared__ u32 lcnt, gbase;
  int s     = blockIdx.x >> 7;   // 16 slices x 128 chunks
  int chunk = blockIdx.x & 127;
  int tid   = threadIdx.x;
  if (tid == 0) lcnt = 0;
  __syncthreads();
  const float4* hp = (const float4*)(heat + (size_t)s*HW + (size_t)chunk*8192);
  // issue all 8 loads back-to-back: 8 KB/wave in flight
  float4 v[8];
  #pragma unroll
  for (int i = 0; i < 8; ++i) v[i] = hp[i*256 + tid];
  #pragma unroll
  for (int i = 0; i < 8; ++i){
    u32 idx0 = (u32)chunk*8192u + (u32)(i*256 + tid)*4u;
    float vals[4] = {v[i].x, v[i].y, v[i].z, v[i].w};
    #pragma unroll
    for (int c = 0; c < 4; ++c){
      u32 bits  = __float_as_uint(vals[c]);
      u32 delta = 0x3F800000u - bits;         // ulps below 1.0
      if (delta < DELTA_THR){
        u32 p = atomicAdd(&lcnt, 1u);         // LDS atomic, rare (~5/block)
        if (p < LCAP) lbuf[p] = make_uint2(bits, idx0 + (u32)c);
        else {                                // overflow: direct global (never on this data)
          u32 gp = atomicAdd(&cnt[s*16], 1u);
          if (gp < CAP) cand[(size_t)s*CAP + gp] = make_uint2(bits, idx0 + (u32)c);
        }
      }
    }
  }
  __syncthreads();
  u32 n = (lcnt < LCAP) ? lcnt : LCAP;
  if (tid == 0) gbase = atomicAdd(&cnt[s*16], n);   // ONE global atomic per block
  __syncthreads();
  for (u32 i = tid; i < n; i += 256){
    u32 p = gbase + i;
    if (p < CAP) cand[(size_t)s*CAP + p] = lbuf[i];
  }
}

// ---------------- K2: dual-sort + merge + decode + NMS, one block per batch --
__global__ __launch_bounds__(1024) void k2_tail(const float* __restrict__ heat,
                                                const u32* __restrict__ cnt,
                                                uint2* cand,
                                                const float* __restrict__ reg,
                                                const float* __restrict__ rots,
                                                const float* __restrict__ rotc,
                                                const float* __restrict__ hei,
                                                const float* __restrict__ dim,
                                                const float* __restrict__ vel,
                                                float* out){
  __shared__ u64 key[8192];          // 64 KiB; adj aliases first 32 KiB later
  __shared__ uint2 topv[2][512];
  __shared__ float xo[512], yo[512], xs_s[512], ys_s[512];
  __shared__ int order[512], vld[512];
  __shared__ int wsum[16];
  __shared__ u64 keepw[8];
  __shared__ u32 lhist[256];
  __shared__ u32 lc;
  __shared__ int t2s;
  u64* adj = key;

  int b = blockIdx.x, t = threadIdx.x;
  u32 nn[2];
  nn[0] = cnt[(2*b+0)*16]; if (nn[0] > CAP2) nn[0] = CAP2;
  nn[1] = cnt[(2*b+1)*16]; if (nn[1] > CAP2) nn[1] = CAP2;

  // ---- exactness fallback (never taken on this data): hist + recollect ----
  for (int sl = 0; sl < 2; ++sl){
    if (nn[sl] >= (u32)KTOP) continue;
    int s = 2*b + sl;
    for (int i = t; i < 256; i += 1024) lhist[i] = 0;
    if (t == 0) lc = 0;
    __syncthreads();
    const float4* hp = (const float4*)(heat + (size_t)s*HW);
    for (int it = 0; it < 256; ++it){
      float4 v = hp[it*1024 + t];
      #pragma unroll
      for (int c = 0; c < 4; ++c){
        float val = (c==0)?v.x:(c==1)?v.y:(c==2)?v.z:v.w;
        u32 bits  = __float_as_uint(val);
        u32 delta = 0x3F800000u - bits;
        u32 bin   = delta >> 16; if (bin > 255u) bin = 255u;
        atomicAdd(&lhist[bin], 1u);
      }
    }
    __syncthreads();
    if (t == 0){
      u32 cum = 0; u32 b1 = 255u;
      for (u32 bb = 0; bb < 256u; ++bb){
        cum += lhist[bb];
        if (cum >= (u32)KTOP){ b1 = bb; break; }
      }
      t2s = (int)(0x3F800000u - ((b1 + 1u) << 16) + 1u);
    }
    __syncthreads();
    int t2 = t2s;
    for (int it = 0; it < 256; ++it){
      float4 v = hp[it*1024 + t];
      u32 idx0 = (u32)(it*1024 + t)*4u;
      #pragma unroll
      for (int c = 0; c < 4; ++c){
        float val = (c==0)?v.x:(c==1)?v.y:(c==2)?v.z:v.w;
        int bits = (int)__float_as_uint(val);   // signed cmp excludes negatives
        if (bits >= t2){
          u32 p = atomicAdd(&lc, 1u);
          if (p < CAP2) cand[(size_t)s*CAP + p] = make_uint2((u32)bits, idx0 + (u32)c);
        }
      }
    }
    __syncthreads();
    nn[sl] = (lc < CAP2) ? lc : CAP2;
    __syncthreads();
  }

  u32 nmax = (nn[0] > nn[1]) ? nn[0] : nn[1];
  int NP = 1024; while (NP < (int)nmax) NP <<= 1;   // <= 4096

  // ---- load both slices' candidates (keyed: value desc, heat-idx asc)
  for (int i = t; i < 2*NP; i += 1024){
    int seg = (i >= NP) ? 1 : 0;
    int ii  = i & (NP - 1);
    u64 k = ~0ull;
    if (ii < (int)nn[seg]){
      uint2 cv = cand[(size_t)(2*b + seg)*CAP + ii];
      k = ((u64)(~cv.x) << 32) | (u64)cv.y;
    }
    key[i] = k;
  }
  // ---- dual independent bitonic sorts (same network, two segments)
  for (int len = 2; len <= NP; len <<= 1){
    for (int stride = len >> 1; stride > 0; stride >>= 1){
      __syncthreads();
      for (int i = t; i < 2*NP; i += 1024){
        int base = i & ~(NP - 1);
        int ii   = i & (NP - 1);
        int jj   = ii ^ stride;
        if (jj > ii){
          u64 a = key[base + ii], bb = key[base + jj];
          bool up = ((ii & len) == 0);
          if ((a > bb) == up){ key[base + ii] = bb; key[base + jj] = a; }
        }
      }
    }
  }
  __syncthreads();
  if (t < 512){
    u64 k0 = key[t];
    topv[0][t] = make_uint2(~(u32)(k0 >> 32), (u32)k0);
  } else {
    u64 k1 = key[NP + (t - 512)];
    topv[1][t-512] = make_uint2(~(u32)(k1 >> 32), (u32)k1);
  }
  __syncthreads();

  // ---- 10-pass bitonic merge (list0 asc, list1 desc; tie-break = c*K pos)
  {
    u64 k;
    if (t < 512){
      k = (t < KTOP) ? (((u64)(~topv[0][t].x) << 32) | (u64)t) : ~0ull;
    } else {
      int p = 511 - (t - 512);
      k = (p < KTOP) ? (((u64)(~topv[1][p].x) << 32) | (u64)(KTOP + p)) : ~0ull;
    }
    key[t] = k;
  }
  for (int stride = 512; stride > 0; stride >>= 1){
    __syncthreads();
    int j = t ^ stride;
    if (t < 1024 && j > t){
      u64 a = key[t], bb = key[j];
      if (a > bb){ key[t] = bb; key[j] = a; }
    }
  }
  __syncthreads();

  u32 myind = 0; float mysc = 0.0f;
  if (t < KTOP){
    u64 k = key[t];
    u32 src = (u32)k;                 // position in concatenated c*K array
    int c = (src >= (u32)KTOP) ? 1 : 0;
    int pos = (int)src - c*KTOP;
    myind = topv[c][pos].y;
    mysc = __uint_as_float(~(u32)(k >> 32));
    out[36000 + b*KTOP + t] = mysc;
    out[40000 + b*KTOP + t] = (float)c;
  }
  __syncthreads();   // key (== adj) free after this point

  // ---- gather + decode + valid
  float x = 0.f, y = 0.f; int v = 0;
  if (t < KTOP){
    u32 ind = myind & (u32)(HW - 1);
    float xs0 = (float)(ind & 1023u);
    float ys0 = (float)(ind >> 10);
    size_t bb = (size_t)b;
    float r0  = reg [(bb*2 + 0)*HW + ind];
    float r1  = reg [(bb*2 + 1)*HW + ind];
    float sn  = rots[ bb       *HW + ind];
    float cs  = rotc[ bb       *HW + ind];
    float he  = hei [ bb       *HW + ind];
    float d0  = dim [(bb*3 + 0)*HW + ind];
    float d1  = dim [(bb*3 + 1)*HW + ind];
    float d2v = dim [(bb*3 + 2)*HW + ind];
    float v0  = vel [(bb*2 + 0)*HW + ind];
    float v1  = vel [(bb*2 + 1)*HW + ind];
    x = xs0 + r0; y = ys0 + r1;
    float rot = atan2f(sn, cs);
    float* bx = out + (size_t)(b*KTOP + t)*9;
    bx[0]=x; bx[1]=y; bx[2]=he; bx[3]=d0; bx[4]=d1; bx[5]=d2v; bx[6]=rot; bx[7]=v0; bx[8]=v1;
    v = ((x >= -100.0f) && (x <= 1124.0f) &&
         (y >= -100.0f) && (y <= 1124.0f) &&
         (he >= -10.0f) && (he <= 10.0f) && (mysc > 0.1f)) ? 1 : 0;
    out[44000 + b*KTOP + t] = v ? 1.0f : 0.0f;
  }
  if (t < 512){ xo[t] = x; yo[t] = y; vld[t] = v; }

  // ---- 1-barrier ballot scan: stable valid-first partition
  u64 bm = __ballot(v != 0);
  int lane = t & 63, wv = t >> 6;
  if (lane == 0) wsum[wv] = __popcll(bm);
  __syncthreads();
  int off = 0, nValid = 0;
  #pragma unroll
  for (int w2 = 0; w2 < 8; ++w2){
    int sv = wsum[w2];
    nValid += sv;
    if (w2 < wv) off += sv;
  }
  int incl = off + __popcll(bm & ((~0ull) >> (63 - lane)));
  if (t < KTOP){
    int excl = incl - v;
    int slot = v ? excl : (nValid + (t - excl));
    order[slot] = t;
  }
  __syncthreads();
  if (t < KTOP){ int p = order[t]; xs_s[t] = xo[p]; ys_s[t] = yo[p]; }
  __syncthreads();

  // ---- adjacency bitmask rows (16 waves), in LDS (aliases key)
  int ln = t & 63;
  for (int i = wv; i < KTOP; i += 16){
    float xi = xs_s[i], yi = ys_s[i];
    #pragma unroll
    for (int jc = 0; jc < 8; ++jc){
      int j = jc*64 + ln;
      bool pred = false;
      if (j < KTOP && j > i){
        float dx = __fsub_rn(xs_s[j], xi);
        float dy = __fsub_rn(ys_s[j], yi);
        float d2 = __fadd_rn(__fmul_rn(dx,dx), __fmul_rn(dy,dy));
        pred = (d2 <= 4.0f);
      }
      u64 m = __ballot(pred);
      if (ln == 0) adj[i*8 + jc] = m;
    }
  }
  __syncthreads();

  // ---- greedy suppression: 1 wave; lanes 0..7 own supp words; readlane bcast
  if (t < 64){
    int ln8 = t & 7;
    u64 supp = 0ull;
    u64 row = adj[ln8];                         // row 0 prefetched
    for (int i = 0; i < KTOP; ++i){
      u64 rown = adj[(i+1 < KTOP ? i+1 : i)*8 + ln8];   // prefetch next
      u32 lo = (u32)supp, hi = (u32)(supp >> 32);
      u32 sel = (i & 32) ? hi : lo;
      u32 wbit = (u32)__builtin_amdgcn_readlane((int)sel, i >> 6);  // uniform lane
      if (!((wbit >> (i & 31)) & 1u)) supp |= row;       // wave-uniform branch
      row = rown;
    }
    if (t < 8){
      u64 kp = ~supp;
      if (t == 7) kp &= ((1ull << 52) - 1ull);  // j in [448,500)
      keepw[t] = kp;
    }
  }
  __syncthreads();

  // ---- cumsum cap at POST_MAX
  if (t == 0){
    int budget = POST_MAX;
    for (int c2 = 0; c2 < 8; ++c2){
      u64 w = keepw[c2];
      int n = __popcll(w);
      if (n <= budget){ budget -= n; }
      else {
        while (n > budget){ w &= ~(1ull << (63 - __clzll(w))); --n; }
        budget = 0;
      }
      keepw[c2] = w;
    }
  }
  __syncthreads();
  if (t < KTOP){
    int bit = (int)((keepw[t >> 6] >> (t & 63)) & 1ull);
    int p = order[t];
    out[48000 + b*KTOP + p] = (bit && vld[p]) ? 1.0f : 0.0f;
  }
}

extern "C" void kernel_launch(void* const* d_in, const int* in_sizes, int n_in,
                              void* d_out, int out_size, void* d_ws, size_t ws_size,
                              hipStream_t stream){
  const float* heat = (const float*)d_in[0];
  const float* reg  = (const float*)d_in[1];
  const float* rots = (const float*)d_in[2];
  const float* rotc = (const float*)d_in[3];
  const float* hei  = (const float*)d_in[4];
  const float* dim  = (const float*)d_in[5];
  const float* vel  = (const float*)d_in[6];
  float* out = (float*)d_out;
  char* ws = (char*)d_ws;
  u32*   cnt   = (u32*)  (ws + WS_CNT);
  uint2* cand  = (uint2*)(ws + WS_CAND);

  hipMemsetAsync(ws, 0, 1024, stream);    // cnt only
  k1_collect <<<2048, 256, 0, stream>>>(heat, cnt, cand);
  k2_tail    <<<8,   1024, 0, stream>>>(heat, cnt, cand, reg, rots, rotc, hei, dim, vel, out);
}

// Round 8
// 116.766 us; speedup vs baseline: 1.4182x; 1.0576x over previous
//
#include <hip/hip_runtime.h>
#include <stdint.h>

typedef unsigned int u32;
typedef unsigned long long u64;

#define HW (1024*1024)
#define KTOP 500
#define CAP 8192u
#define LCAP 256u
#define POST_MAX 83
#define DELTA_THR 9728u     // v > 1 - 9728*2^-24 ~ 0.99942; E[count/slice] ~ 580

// workspace byte offsets
#define WS_CNT   0          // u32[16*16]  one counter per 64B line per slice
#define WS_CAND  32768      // uint2[16*8192] -> ends 1081344
#define WS_SORT  1081344    // uint2[16*512] -> ends 1146880

// out layout (floats): boxes[0,36000) scores[36000,40000) clses[40000,44000)
// valid[44000,48000) keep[48000,52000)

// ---------------- K1: streaming collect, batched loads, no fences ------------
__global__ __launch_bounds__(256) void k1_collect(const float* __restrict__ heat,
                                                  u32* cnt, uint2* cand){
  __shared__ uint2 lbuf[LCAP];
  __shared__ u32 lcnt, gbase;
  int s     = blockIdx.x >> 7;   // 16 slices x 128 chunks
  int chunk = blockIdx.x & 127;
  int tid   = threadIdx.x;
  if (tid == 0) lcnt = 0;
  __syncthreads();
  const float4* hp = (const float4*)(heat + (size_t)s*HW + (size_t)chunk*8192);
  float4 v[8];
  #pragma unroll
  for (int i = 0; i < 8; ++i) v[i] = hp[i*256 + tid];
  #pragma unroll
  for (int i = 0; i < 8; ++i){
    u32 idx0 = (u32)chunk*8192u + (u32)(i*256 + tid)*4u;
    float vals[4] = {v[i].x, v[i].y, v[i].z, v[i].w};
    #pragma unroll
    for (int c = 0; c < 4; ++c){
      u32 bits  = __float_as_uint(vals[c]);
      u32 delta = 0x3F800000u - bits;         // ulps below 1.0
      if (delta < DELTA_THR){
        u32 p = atomicAdd(&lcnt, 1u);         // LDS atomic, rare (~5/block)
        if (p < LCAP) lbuf[p] = make_uint2(bits, idx0 + (u32)c);
        else {
          u32 gp = atomicAdd(&cnt[s*16], 1u);
          if (gp < CAP) cand[(size_t)s*CAP + gp] = make_uint2(bits, idx0 + (u32)c);
        }
      }
    }
  }
  __syncthreads();
  u32 n = (lcnt < LCAP) ? lcnt : LCAP;
  if (tid == 0) gbase = atomicAdd(&cnt[s*16], n);   // ONE global atomic per block
  __syncthreads();
  for (u32 i = tid; i < n; i += 256){
    u32 p = gbase + i;
    if (p < CAP) cand[(size_t)s*CAP + p] = lbuf[i];
  }
}

// ---------------- KR: per-slice exact top-500 via rank-by-count --------------
__global__ __launch_bounds__(1024) void kR_rank(const float* __restrict__ heat,
                                                const u32* __restrict__ cnt,
                                                uint2* cand, uint2* sorted){
  __shared__ __align__(16) u64 lkey[CAP];   // 64 KiB
  __shared__ u32 lhist[256];
  __shared__ u32 lc;
  __shared__ int t2s;
  int s = blockIdx.x, t = threadIdx.x;
  u32 n = cnt[s*16]; if (n > CAP) n = CAP;

  if (n < (u32)KTOP){
    // ---- exactness fallback (never taken on this data): hist + recollect ----
    if (t < 256) lhist[t] = 0;
    if (t == 0) lc = 0;
    __syncthreads();
    const float4* hp = (const float4*)(heat + (size_t)s*HW);
    for (int it = 0; it < 256; ++it){
      float4 v = hp[it*1024 + t];
      #pragma unroll
      for (int c = 0; c < 4; ++c){
        float val = (c==0)?v.x:(c==1)?v.y:(c==2)?v.z:v.w;
        u32 bits  = __float_as_uint(val);
        u32 delta = 0x3F800000u - bits;
        u32 bin   = delta >> 16; if (bin > 255u) bin = 255u;
        atomicAdd(&lhist[bin], 1u);
      }
    }
    __syncthreads();
    if (t == 0){
      u32 cum = 0; u32 b1 = 255u;
      for (u32 bb = 0; bb < 256u; ++bb){
        cum += lhist[bb];
        if (cum >= (u32)KTOP){ b1 = bb; break; }
      }
      t2s = (int)(0x3F800000u - ((b1 + 1u) << 16) + 1u);
    }
    __syncthreads();
    int t2 = t2s;
    for (int it = 0; it < 256; ++it){
      float4 v = hp[it*1024 + t];
      u32 idx0 = (u32)(it*1024 + t)*4u;
      #pragma unroll
      for (int c = 0; c < 4; ++c){
        float val = (c==0)?v.x:(c==1)?v.y:(c==2)?v.z:v.w;
        int bits = (int)__float_as_uint(val);   // signed cmp excludes negatives
        if (bits >= t2){
          u32 p = atomicAdd(&lc, 1u);
          if (p < CAP) cand[(size_t)s*CAP + p] = make_uint2((u32)bits, idx0 + (u32)c);
        }
      }
    }
    __syncthreads();
    n = (lc < CAP) ? lc : CAP;
  }

  // ---- load keys: (value desc, heat-idx asc) as ascending u64 ----
  for (u32 i = t; i < n; i += 1024){
    uint2 cv = cand[(size_t)s*CAP + i];
    lkey[i] = ((u64)(~cv.x) << 32) | (u64)cv.y;
  }
  __syncthreads();

  // ---- rank-by-count: rank(e) = #{e' : key(e') < key(e)} ----
  const ulonglong2* lk2 = (const ulonglong2*)lkey;
  for (u32 base = 0; base < n; base += 1024){
    u32 me = base + t;
    if (me < n){
      u64 k0 = lkey[me];
      u32 r = 0;
      u32 half = n >> 1;
      for (u32 j = 0; j < half; ++j){
        ulonglong2 kk = lk2[j];               // LDS broadcast read
        r += (kk.x < k0) ? 1u : 0u;
        r += (kk.y < k0) ? 1u : 0u;
      }
      if (n & 1u) r += (lkey[n-1] < k0) ? 1u : 0u;
      if (r < 512u)
        sorted[s*512 + (int)r] = make_uint2(~(u32)(k0 >> 32), (u32)k0);
    }
  }
}

// ---------------- KT: merge(binary search) + decode + circle NMS -------------
__global__ __launch_bounds__(1024) void kT_tail(const uint2* __restrict__ sorted,
                                                const float* __restrict__ reg,
                                                const float* __restrict__ rots,
                                                const float* __restrict__ rotc,
                                                const float* __restrict__ hei,
                                                const float* __restrict__ dim,
                                                const float* __restrict__ vel,
                                                float* out){
  __shared__ u64 k2a[512], k2b[512];
  __shared__ uint2 fin[512];           // .x=score bits, .y=idx | cls<<20
  __shared__ float xo[512], yo[512], xs_s[512], ys_s[512];
  __shared__ int order[512], vld[512];
  __shared__ int wsum[16];
  __shared__ u64 adjb[4096];           // 32 KiB
  __shared__ u64 keepw[8];
  int b = blockIdx.x, t = threadIdx.x;

  // ---- phase 1: load both sorted lists, build level-2 keys (score desc, concat-pos asc)
  uint2 mye = make_uint2(0u, 0u);
  if (t < 512){
    mye = sorted[(b*2 + 0)*512 + t];
    k2a[t] = ((u64)(~mye.x) << 32) | (u64)t;
  } else {
    int p = t - 512;
    mye = sorted[(b*2 + 1)*512 + p];
    k2b[p] = ((u64)(~mye.x) << 32) | (u64)(KTOP + p);
  }
  __syncthreads();

  // ---- phase 2: merged rank = own rank + lower_bound in other list
  if (t < KTOP){
    u64 K = k2a[t];
    int lo = 0, hi = KTOP;
    while (lo < hi){ int mid = (lo + hi) >> 1; if (k2b[mid] < K) lo = mid + 1; else hi = mid; }
    int m = t + lo;
    if (m < KTOP){
      fin[m] = make_uint2(mye.x, mye.y & 0xFFFFFu);
      out[36000 + b*KTOP + m] = __uint_as_float(mye.x);
      out[40000 + b*KTOP + m] = 0.0f;
    }
  } else if (t >= 512 && t < 512 + KTOP){
    int p = t - 512;
    u64 K = k2b[p];
    int lo = 0, hi = KTOP;
    while (lo < hi){ int mid = (lo + hi) >> 1; if (k2a[mid] < K) lo = mid + 1; else hi = mid; }
    int m = p + lo;
    if (m < KTOP){
      fin[m] = make_uint2(mye.x, (mye.y & 0xFFFFFu) | (1u << 20));
      out[36000 + b*KTOP + m] = __uint_as_float(mye.x);
      out[40000 + b*KTOP + m] = 1.0f;
    }
  }
  __syncthreads();

  // ---- phase 3: gather + decode + valid
  float x = 0.f, y = 0.f; int v = 0;
  if (t < KTOP){
    uint2 e = fin[t];
    u32 ind = e.y & 0xFFFFFu;
    float mysc = __uint_as_float(e.x);
    float xs0 = (float)(ind & 1023u);
    float ys0 = (float)(ind >> 10);
    size_t bb = (size_t)b;
    float r0  = reg [(bb*2 + 0)*HW + ind];
    float r1  = reg [(bb*2 + 1)*HW + ind];
    float sn  = rots[ bb       *HW + ind];
    float cs  = rotc[ bb       *HW + ind];
    float he  = hei [ bb       *HW + ind];
    float d0  = dim [(bb*3 + 0)*HW + ind];
    float d1  = dim [(bb*3 + 1)*HW + ind];
    float d2v = dim [(bb*3 + 2)*HW + ind];
    float v0  = vel [(bb*2 + 0)*HW + ind];
    float v1  = vel [(bb*2 + 1)*HW + ind];
    x = xs0 + r0; y = ys0 + r1;
    float rot = atan2f(sn, cs);
    float* bx = out + (size_t)(b*KTOP + t)*9;
    bx[0]=x; bx[1]=y; bx[2]=he; bx[3]=d0; bx[4]=d1; bx[5]=d2v; bx[6]=rot; bx[7]=v0; bx[8]=v1;
    v = ((x >= -100.0f) && (x <= 1124.0f) &&
         (y >= -100.0f) && (y <= 1124.0f) &&
         (he >= -10.0f) && (he <= 10.0f) && (mysc > 0.1f)) ? 1 : 0;
    out[44000 + b*KTOP + t] = v ? 1.0f : 0.0f;
  }
  if (t < 512){ xo[t] = x; yo[t] = y; vld[t] = v; }

  // ---- phase 4: 1-barrier ballot scan, stable valid-first partition
  u64 bm = __ballot(v != 0);
  int lane = t & 63, wv = t >> 6;
  if (lane == 0) wsum[wv] = __popcll(bm);
  __syncthreads();
  int off = 0, nValid = 0;
  #pragma unroll
  for (int w2 = 0; w2 < 8; ++w2){
    int sv = wsum[w2];
    nValid += sv;
    if (w2 < wv) off += sv;
  }
  int incl = off + __popcll(bm & ((~0ull) >> (63 - lane)));
  if (t < KTOP){
    int excl = incl - v;
    int slot = v ? excl : (nValid + (t - excl));
    order[slot] = t;
  }
  __syncthreads();
  if (t < KTOP){ int p = order[t]; xs_s[t] = xo[p]; ys_s[t] = yo[p]; }
  __syncthreads();

  // ---- phase 5: triangular adjacency bitmask rows (16 waves)
  int ln = t & 63;
  for (int i = wv; i < KTOP; i += 16){
    float xi = xs_s[i], yi = ys_s[i];
    for (int jc = (i >> 6); jc < 8; ++jc){
      int j = jc*64 + ln;
      bool pred = false;
      if (j < KTOP && j > i){
        float dx = __fsub_rn(xs_s[j], xi);
        float dy = __fsub_rn(ys_s[j], yi);
        float d2 = __fadd_rn(__fmul_rn(dx,dx), __fmul_rn(dy,dy));
        pred = (d2 <= 4.0f);
      }
      u64 m = __ballot(pred);
      if (ln == 0) adjb[i*8 + jc] = m;
    }
  }
  __syncthreads();

  // ---- phase 6: greedy suppression (1 wave; lanes 0..7 own supp words)
  if (t < 64){
    int ln8 = t & 7;
    u64 supp = 0ull;
    for (int i = 0; i < KTOP; ++i){
      u64 row = adjb[i*8 + ln8];
      row = (ln8 >= (i >> 6)) ? row : 0ull;     // triangular: lower words undefined
      if (t >= 8) row = 0ull;
      u32 lo = (u32)supp, hi = (u32)(supp >> 32);
      u32 sel = (i & 32) ? hi : lo;
      u32 wbit = (u32)__builtin_amdgcn_readlane((int)sel, i >> 6);  // uniform lane
      if (!((wbit >> (i & 31)) & 1u)) supp |= row;                  // wave-uniform branch
    }
    if (t < 8){
      u64 kp = ~supp;
      if (t == 7) kp &= ((1ull << 52) - 1ull);  // j in [448,500)
      keepw[t] = kp;
    }
  }
  __syncthreads();

  // ---- phase 7: cumsum cap at POST_MAX
  if (t == 0){
    int budget = POST_MAX;
    for (int c2 = 0; c2 < 8; ++c2){
      u64 w = keepw[c2];
      int n = __popcll(w);
      if (n <= budget){ budget -= n; }
      else {
        while (n > budget){ w &= ~(1ull << (63 - __clzll(w))); --n; }
        budget = 0;
      }
      keepw[c2] = w;
    }
  }
  __syncthreads();
  if (t < KTOP){
    int bit = (int)((keepw[t >> 6] >> (t & 63)) & 1ull);
    int p = order[t];
    out[48000 + b*KTOP + p] = (bit && vld[p]) ? 1.0f : 0.0f;
  }
}

extern "C" void kernel_launch(void* const* d_in, const int* in_sizes, int n_in,
                              void* d_out, int out_size, void* d_ws, size_t ws_size,
                              hipStream_t stream){
  const float* heat = (const float*)d_in[0];
  const float* reg  = (const float*)d_in[1];
  const float* rots = (const float*)d_in[2];
  const float* rotc = (const float*)d_in[3];
  const float* hei  = (const float*)d_in[4];
  const float* dim  = (const float*)d_in[5];
  const float* vel  = (const float*)d_in[6];
  float* out = (float*)d_out;
  char* ws = (char*)d_ws;
  u32*   cnt    = (u32*)  (ws + WS_CNT);
  uint2* cand   = (uint2*)(ws + WS_CAND);
  uint2* sorted = (uint2*)(ws + WS_SORT);

  hipMemsetAsync(ws, 0, 1024, stream);    // cnt only
  k1_collect <<<2048, 256, 0, stream>>>(heat, cnt, cand);
  kR_rank    <<<16,  1024, 0, stream>>>(heat, cnt, cand, sorted);
  kT_tail    <<<8,   1024, 0, stream>>>(sorted, reg, rots, rotc, hei, dim, vel, out);
}

// Round 10
// 61.884 us; speedup vs baseline: 2.6760x; 1.8869x over previous
//
#include <hip/hip_runtime.h>
#include <stdint.h>

typedef unsigned int u32;
typedef unsigned long long u64;

#define HW (1024*1024)
#define KTOP 500
#define CAP 8192u
#define LCAP 256u
#define POST_MAX 83
#define DELTA_THR 9728u     // v > 1 - 9728*2^-24 ~ 0.99942; E[count/slice] ~ 580

// workspace byte offsets
#define WS_CNT   0          // u32[16*16]  one counter per 64B line per slice
#define WS_CAND  32768      // uint2[16*8192] -> ends 1081344
#define WS_SORT  1081344    // uint2[16*512] -> ends 1146880
#define WS_XY    1146880    // float2[8*512] -> ends 1179648
#define WS_ORDV  1179648    // u32[8*512] -> ends 1196032
#define WS_NV    1196032    // u32[8]

// out layout (floats): boxes[0,36000) scores[36000,40000) clses[40000,44000)
// valid[44000,48000) keep[48000,52000)

// ---------------- K1: streaming collect, batched loads, no fences ------------
__global__ __launch_bounds__(256) void k1_collect(const float* __restrict__ heat,
                                                  u32* cnt, uint2* cand){
  __shared__ uint2 lbuf[LCAP];
  __shared__ u32 lcnt, gbase;
  int s     = blockIdx.x >> 7;   // 16 slices x 128 chunks
  int chunk = blockIdx.x & 127;
  int tid   = threadIdx.x;
  if (tid == 0) lcnt = 0;
  __syncthreads();
  const float4* hp = (const float4*)(heat + (size_t)s*HW + (size_t)chunk*8192);
  float4 v[8];
  #pragma unroll
  for (int i = 0; i < 8; ++i) v[i] = hp[i*256 + tid];
  #pragma unroll
  for (int i = 0; i < 8; ++i){
    u32 idx0 = (u32)chunk*8192u + (u32)(i*256 + tid)*4u;
    float vals[4] = {v[i].x, v[i].y, v[i].z, v[i].w};
    #pragma unroll
    for (int c = 0; c < 4; ++c){
      u32 bits  = __float_as_uint(vals[c]);
      u32 delta = 0x3F800000u - bits;         // ulps below 1.0
      if (delta < DELTA_THR){
        u32 p = atomicAdd(&lcnt, 1u);         // LDS atomic, rare (~5/block)
        if (p < LCAP) lbuf[p] = make_uint2(bits, idx0 + (u32)c);
        else {
          u32 gp = atomicAdd(&cnt[s*16], 1u);
          if (gp < CAP) cand[(size_t)s*CAP + gp] = make_uint2(bits, idx0 + (u32)c);
        }
      }
    }
  }
  __syncthreads();
  u32 n = (lcnt < LCAP) ? lcnt : LCAP;
  if (tid == 0) gbase = atomicAdd(&cnt[s*16], n);   // ONE global atomic per block
  __syncthreads();
  for (u32 i = tid; i < n; i += 256){
    u32 p = gbase + i;
    if (p < CAP) cand[(size_t)s*CAP + p] = lbuf[i];
  }
}

// ---------------- KR: per-slice exact top-500 via rank-by-count --------------
// 2 blocks per slice (each ranks half the candidates; both load all keys).
__global__ __launch_bounds__(1024) void kR_rank(const float* __restrict__ heat,
                                                const u32* __restrict__ cnt,
                                                uint2* cand, uint2* sorted){
  __shared__ __align__(16) u64 lkey[CAP];   // 64 KiB
  __shared__ u32 lhist[256];
  __shared__ u32 lc;
  __shared__ int t2s;
  int s = blockIdx.x >> 1, h = blockIdx.x & 1, t = threadIdx.x;
  u32 n = cnt[s*16]; if (n > CAP) n = CAP;

  if (n < (u32)KTOP){
    if (h) return;        // fallback handled entirely by block h==0
    // ---- exactness fallback (never taken on this data): hist + recollect ----
    if (t < 256) lhist[t] = 0;
    if (t == 0) lc = 0;
    __syncthreads();
    const float4* hp = (const float4*)(heat + (size_t)s*HW);
    for (int it = 0; it < 256; ++it){
      float4 v = hp[it*1024 + t];
      #pragma unroll
      for (int c = 0; c < 4; ++c){
        float val = (c==0)?v.x:(c==1)?v.y:(c==2)?v.z:v.w;
        u32 bits  = __float_as_uint(val);
        u32 delta = 0x3F800000u - bits;
        u32 bin   = delta >> 16; if (bin > 255u) bin = 255u;
        atomicAdd(&lhist[bin], 1u);
      }
    }
    __syncthreads();
    if (t == 0){
      u32 cum = 0; u32 b1 = 255u;
      for (u32 bb = 0; bb < 256u; ++bb){
        cum += lhist[bb];
        if (cum >= (u32)KTOP){ b1 = bb; break; }
      }
      t2s = (int)(0x3F800000u - ((b1 + 1u) << 16) + 1u);
    }
    __syncthreads();
    int t2 = t2s;
    for (int it = 0; it < 256; ++it){
      float4 v = hp[it*1024 + t];
      u32 idx0 = (u32)(it*1024 + t)*4u;
      #pragma unroll
      for (int c = 0; c < 4; ++c){
        float val = (c==0)?v.x:(c==1)?v.y:(c==2)?v.z:v.w;
        int bits = (int)__float_as_uint(val);   // signed cmp excludes negatives
        if (bits >= t2){
          u32 p = atomicAdd(&lc, 1u);
          if (p < CAP) cand[(size_t)s*CAP + p] = make_uint2((u32)bits, idx0 + (u32)c);
        }
      }
    }
    __syncthreads();
    n = (lc < CAP) ? lc : CAP;
  }

  // ---- load keys: (value desc, heat-idx asc) as ascending u64 ----
  for (u32 i = t; i < n; i += 1024){
    uint2 cv = cand[(size_t)s*CAP + i];
    lkey[i] = ((u64)(~cv.x) << 32) | (u64)cv.y;
  }
  __syncthreads();

  // ---- rank-by-count over this block's half: rank = #{key' < key} ----
  u32 lo = (n < (u32)KTOP) ? 0u : (u32)h * ((n + 1u) >> 1);
  u32 hi = (n < (u32)KTOP) ? n : ((h ? n : ((n + 1u) >> 1)));
  const ulonglong2* lk2 = (const ulonglong2*)lkey;
  for (u32 me = lo + t; me < hi; me += 1024){
    u64 k0 = lkey[me];
    u32 r = 0;
    u32 half = n >> 1;
    for (u32 j = 0; j < half; ++j){
      ulonglong2 kk = lk2[j];               // LDS broadcast read
      r += (kk.x < k0) ? 1u : 0u;
      r += (kk.y < k0) ? 1u : 0u;
    }
    if (n & 1u) r += (lkey[n-1] < k0) ? 1u : 0u;
    if (r < 512u)
      sorted[s*512 + (int)r] = make_uint2(~(u32)(k0 >> 32), (u32)k0);
  }
}

// ---------------- KT1: merge(binary search) + decode + partition -------------
__global__ __launch_bounds__(1024) void kT1_prep(const uint2* __restrict__ sorted,
                                                 const float* __restrict__ reg,
                                                 const float* __restrict__ rots,
                                                 const float* __restrict__ rotc,
                                                 const float* __restrict__ hei,
                                                 const float* __restrict__ dim,
                                                 const float* __restrict__ vel,
                                                 float* out, float2* xyg,
                                                 u32* ordvg, u32* nvg){
  __shared__ u64 k2a[512], k2b[512];
  __shared__ uint2 fin[512];           // .x=score bits, .y=idx | cls<<20
  __shared__ float xo[512], yo[512];
  __shared__ int order[512], vld[512];
  __shared__ int wsum[16];
  int b = blockIdx.x, t = threadIdx.x;

  // ---- phase 1: load both sorted lists, level-2 keys (score desc, concat-pos asc)
  uint2 mye = make_uint2(0u, 0u);
  if (t < 512){
    mye = sorted[(b*2 + 0)*512 + t];
    k2a[t] = ((u64)(~mye.x) << 32) | (u64)t;
  } else {
    int p = t - 512;
    mye = sorted[(b*2 + 1)*512 + p];
    k2b[p] = ((u64)(~mye.x) << 32) | (u64)(KTOP + p);
  }
  __syncthreads();

  // ---- phase 2: merged rank = own rank + lower_bound in other list
  if (t < KTOP){
    u64 K = k2a[t];
    int lo = 0, hi = KTOP;
    while (lo < hi){ int mid = (lo + hi) >> 1; if (k2b[mid] < K) lo = mid + 1; else hi = mid; }
    int m = t + lo;
    if (m < KTOP){
      fin[m] = make_uint2(mye.x, mye.y & 0xFFFFFu);
      out[36000 + b*KTOP + m] = __uint_as_float(mye.x);
      out[40000 + b*KTOP + m] = 0.0f;
    }
  } else if (t >= 512 && t < 512 + KTOP){
    int p = t - 512;
    u64 K = k2b[p];
    int lo = 0, hi = KTOP;
    while (lo < hi){ int mid = (lo + hi) >> 1; if (k2a[mid] < K) lo = mid + 1; else hi = mid; }
    int m = p + lo;
    if (m < KTOP){
      fin[m] = make_uint2(mye.x, (mye.y & 0xFFFFFu) | (1u << 20));
      out[36000 + b*KTOP + m] = __uint_as_float(mye.x);
      out[40000 + b*KTOP + m] = 1.0f;
    }
  }
  __syncthreads();

  // ---- phase 3: gather + decode + valid
  float x = 0.f, y = 0.f; int v = 0;
  if (t < KTOP){
    uint2 e = fin[t];
    u32 ind = e.y & 0xFFFFFu;
    float mysc = __uint_as_float(e.x);
    float xs0 = (float)(ind & 1023u);
    float ys0 = (float)(ind >> 10);
    size_t bb = (size_t)b;
    float r0  = reg [(bb*2 + 0)*HW + ind];
    float r1  = reg [(bb*2 + 1)*HW + ind];
    float sn  = rots[ bb       *HW + ind];
    float cs  = rotc[ bb       *HW + ind];
    float he  = hei [ bb       *HW + ind];
    float d0  = dim [(bb*3 + 0)*HW + ind];
    float d1  = dim [(bb*3 + 1)*HW + ind];
    float d2v = dim [(bb*3 + 2)*HW + ind];
    float v0  = vel [(bb*2 + 0)*HW + ind];
    float v1  = vel [(bb*2 + 1)*HW + ind];
    x = xs0 + r0; y = ys0 + r1;
    float rot = atan2f(sn, cs);
    float* bx = out + (size_t)(b*KTOP + t)*9;
    bx[0]=x; bx[1]=y; bx[2]=he; bx[3]=d0; bx[4]=d1; bx[5]=d2v; bx[6]=rot; bx[7]=v0; bx[8]=v1;
    v = ((x >= -100.0f) && (x <= 1124.0f) &&
         (y >= -100.0f) && (y <= 1124.0f) &&
         (he >= -10.0f) && (he <= 10.0f) && (mysc > 0.1f)) ? 1 : 0;
    out[44000 + b*KTOP + t] = v ? 1.0f : 0.0f;
  }
  if (t < 512){ xo[t] = x; yo[t] = y; vld[t] = v; }

  // ---- phase 4: 1-barrier ballot scan, stable valid-first partition
  u64 bm = __ballot(v != 0);
  int lane = t & 63, wv = t >> 6;
  if (lane == 0) wsum[wv] = __popcll(bm);
  __syncthreads();
  int off = 0, nValid = 0;
  #pragma unroll
  for (int w2 = 0; w2 < 8; ++w2){
    int sv = wsum[w2];
    nValid += sv;
    if (w2 < wv) off += sv;
  }
  int incl = off + __popcll(bm & ((~0ull) >> (63 - lane)));
  if (t < KTOP){
    int excl = incl - v;
    int slot = v ? excl : (nValid + (t - excl));
    order[slot] = t;
  }
  __syncthreads();

  // ---- phase 5: emit ordered points + order/valid for kT2
  if (t < KTOP){
    int p = order[t];
    xyg[b*512 + t] = make_float2(xo[p], yo[p]);
    ordvg[b*512 + t] = (u32)p | ((u32)vld[p] << 31);
  } else if (t < 512){
    xyg[b*512 + t] = make_float2(1e30f, 1e30f);
    ordvg[b*512 + t] = 0u;
  }
  if (t == 0) nvg[b] = (u32)nValid;
}

// ---------------- KT2: greedy kept-set scan (1 wave) + cap + keep-write ------
__global__ __launch_bounds__(64) void kT2_greedy(const float2* __restrict__ xyg,
                                                 const u32* __restrict__ ordvg,
                                                 const u32* __restrict__ nvg,
                                                 float* out){
  __shared__ float2 pts[512];
  __shared__ u64 keepw[8];
  int b = blockIdx.x, t = threadIdx.x;   // 64 threads = 1 wave
  const float2* src = xyg + b*512;
  for (int i = t; i < 512; i += 64) pts[i] = src[i];
  if (t < 8) keepw[t] = 0ull;
  __syncthreads();
  int nv = (int)nvg[b];

  // kept set in lane registers: lane k of set0 holds kept #k, set1 holds #64+k.
  // pts[i] is read at a wave-uniform address -> p is identical in all lanes, so
  // "append to lane #count" is a predicated per-lane assignment (count uniform).
  float kx0 = 1e30f, ky0 = 1e30f, kx1 = 1e30f, ky1 = 1e30f;
  int count = 0;
  u64 curw = 0ull;
  int i = 0;
  float2 pcur = pts[0];
  float2 pnxt = pts[1];
  for (i = 0; i < nv; ++i){
    float2 p = pcur;
    pcur = pnxt;
    pnxt = pts[(i + 2 < 512) ? (i + 2) : 511];   // prefetch 2 ahead
    float dx0 = __fsub_rn(kx0, p.x), dy0 = __fsub_rn(ky0, p.y);
    float dx1 = __fsub_rn(kx1, p.x), dy1 = __fsub_rn(ky1, p.y);
    float d20 = __fadd_rn(__fmul_rn(dx0,dx0), __fmul_rn(dy0,dy0));
    float d21 = __fadd_rn(__fmul_rn(dx1,dx1), __fmul_rn(dy1,dy1));
    bool nearby = (d20 <= 4.0f) || (d21 <= 4.0f);
    if (!__any(nearby)){
      // keep candidate i: append (p.x,p.y) to the kept set
      curw |= (1ull << (i & 63));
      if (count < 64){
        if (t == count){ kx0 = p.x; ky0 = p.y; }
      } else {
        if (t == count - 64){ kx1 = p.x; ky1 = p.y; }
      }
      ++count;
      if (count == POST_MAX) break;   // cap: later entries can never be kept
    }
    if ((i & 63) == 63){
      if (t == 0) keepw[i >> 6] |= curw;
      curw = 0ull;
    }
  }
  if (t == 0 && curw != 0ull){
    int wi = i >> 6; if (wi > 7) wi = 7;
    keepw[wi] |= curw;
  }
  __syncthreads();

  for (int e = t; e < KTOP; e += 64){
    int bit = (int)((keepw[e >> 6] >> (e & 63)) & 1ull);
    u32 pv = ordvg[b*512 + e];
    int p = (int)(pv & 511u);
    out[48000 + b*KTOP + p] = (bit && (pv >> 31)) ? 1.0f : 0.0f;
  }
}

extern "C" void kernel_launch(void* const* d_in, const int* in_sizes, int n_in,
                              void* d_out, int out_size, void* d_ws, size_t ws_size,
                              hipStream_t stream){
  const float* heat = (const float*)d_in[0];
  const float* reg  = (const float*)d_in[1];
  const float* rots = (const float*)d_in[2];
  const float* rotc = (const float*)d_in[3];
  const float* hei  = (const float*)d_in[4];
  const float* dim  = (const float*)d_in[5];
  const float* vel  = (const float*)d_in[6];
  float* out = (float*)d_out;
  char* ws = (char*)d_ws;
  u32*    cnt    = (u32*)   (ws + WS_CNT);
  uint2*  cand   = (uint2*) (ws + WS_CAND);
  uint2*  sorted = (uint2*) (ws + WS_SORT);
  float2* xyg    = (float2*)(ws + WS_XY);
  u32*    ordvg  = (u32*)   (ws + WS_ORDV);
  u32*    nvg    = (u32*)   (ws + WS_NV);

  (void)hipMemsetAsync(ws, 0, 1024, stream);    // cnt only
  k1_collect <<<2048, 256, 0, stream>>>(heat, cnt, cand);
  kR_rank    <<<32,  1024, 0, stream>>>(heat, cnt, cand, sorted);
  kT1_prep   <<<8,   1024, 0, stream>>>(sorted, reg, rots, rotc, hei, dim, vel, out, xyg, ordvg, nvg);
  kT2_greedy <<<8,     64, 0, stream>>>(xyg, ordvg, nvg, out);
}

// Round 11
// 54.825 us; speedup vs baseline: 3.0206x; 1.1288x over previous
//
#include <hip/hip_runtime.h>
#include <stdint.h>

typedef unsigned int u32;
typedef unsigned long long u64;

#define HW (1024*1024)
#define KTOP 500
#define CAP 8192u
#define POST_MAX 83
#define DELTA_THR 9728u     // v > 1 - 9728*2^-24 ~ 0.99942; E[count/slice] ~ 580

// workspace byte offsets
#define WS_CNT2  0          // u32[16*128] = 8 KB (every slot written every run)
#define WS_CAND  32768      // uint2[16*8192] -> ends 1081344
#define WS_SORT  1081344    // uint2[16*512] -> ends 1146880

// out layout (floats): boxes[0,36000) scores[36000,40000) clses[40000,44000)
// valid[44000,48000) keep[48000,52000)

// ---------------- K1: streaming collect, fixed per-chunk slots, NO atomics ---
__global__ __launch_bounds__(256) void k1_collect(const float* __restrict__ heat,
                                                  u32* cnt2, uint2* cand){
  __shared__ uint2 lbuf[64];
  __shared__ u32 lcnt;
  int s     = blockIdx.x >> 7;   // 16 slices x 128 chunks
  int chunk = blockIdx.x & 127;
  int tid   = threadIdx.x;
  if (tid == 0) lcnt = 0;
  __syncthreads();
  const float4* hp = (const float4*)(heat + (size_t)s*HW + (size_t)chunk*8192);
  float4 v[8];
  #pragma unroll
  for (int i = 0; i < 8; ++i) v[i] = hp[i*256 + tid];
  #pragma unroll
  for (int i = 0; i < 8; ++i){
    u32 idx0 = (u32)chunk*8192u + (u32)(i*256 + tid)*4u;
    float vals[4] = {v[i].x, v[i].y, v[i].z, v[i].w};
    #pragma unroll
    for (int c = 0; c < 4; ++c){
      u32 bits  = __float_as_uint(vals[c]);
      u32 delta = 0x3F800000u - bits;         // ulps below 1.0
      if (delta < DELTA_THR){                 // E ~ 4.8 per chunk
        u32 p = atomicAdd(&lcnt, 1u);         // LDS atomic only
        if (p < 64u) lbuf[p] = make_uint2(bits, idx0 + (u32)c);
      }
    }
  }
  __syncthreads();
  u32 n = lcnt;
  u32 stored = (n < 64u) ? n : 64u;
  if (tid < stored) cand[(size_t)s*CAP + (u32)chunk*64u + tid] = lbuf[tid];
  if (tid == 0) cnt2[s*128 + chunk] = stored | ((n > 64u) ? 0x80000000u : 0u);
}

// ---------------- KR: gather slots + exact top-500 via rank-by-count ---------
// 2 blocks per slice (each ranks half; both build the full key array).
__global__ __launch_bounds__(1024) void kR_rank(const float* __restrict__ heat,
                                                const u32* __restrict__ cnt2,
                                                uint2* cand, uint2* sorted){
  __shared__ __align__(16) u64 lkey[CAP];   // 64 KiB
  __shared__ u32 coff[129];
  __shared__ u32 lhist[256];
  __shared__ u32 lc;
  __shared__ int t2s;
  __shared__ u32 meta;
  int s = blockIdx.x >> 1, h = blockIdx.x & 1, t = threadIdx.x;

  if (t == 0){
    u32 tot = 0, ov = 0;
    for (int c = 0; c < 128; ++c){
      u32 w = cnt2[s*128 + c];
      ov |= (w >> 31);
      coff[c] = tot;
      tot += (w & 0x7FFFFFFFu);
    }
    coff[128] = tot;
    meta = tot | (ov << 31);
  }
  __syncthreads();
  u32 total = meta & 0x7FFFFFFFu;
  bool fb = ((meta >> 31) != 0u) || (total < (u32)KTOP);
  u32 n;

  if (!fb){
    n = total;
    // gather per-chunk runs into compact key array
    for (u32 i = t; i < CAP; i += 1024){
      u32 c = i >> 6, j = i & 63u;
      u32 cnt_c = coff[c+1] - coff[c];
      if (j < cnt_c){
        uint2 cv = cand[(size_t)s*CAP + i];
        lkey[coff[c] + j] = ((u64)(~cv.x) << 32) | (u64)cv.y;   // value desc, idx asc
      }
    }
    __syncthreads();
  } else {
    if (h) return;        // fallback handled entirely by block h==0
    // ---- exactness fallback (never taken on this data): hist + recollect ----
    if (t < 256) lhist[t] = 0;
    if (t == 0) lc = 0;
    __syncthreads();
    const float4* hp = (const float4*)(heat + (size_t)s*HW);
    for (int it = 0; it < 256; ++it){
      float4 v = hp[it*1024 + t];
      #pragma unroll
      for (int c = 0; c < 4; ++c){
        float val = (c==0)?v.x:(c==1)?v.y:(c==2)?v.z:v.w;
        u32 bits  = __float_as_uint(val);
        u32 delta = 0x3F800000u - bits;
        u32 bin   = delta >> 16; if (bin > 255u) bin = 255u;
        atomicAdd(&lhist[bin], 1u);
      }
    }
    __syncthreads();
    if (t == 0){
      u32 cum = 0; u32 b1 = 255u;
      for (u32 bb = 0; bb < 256u; ++bb){
        cum += lhist[bb];
        if (cum >= (u32)KTOP){ b1 = bb; break; }
      }
      t2s = (int)(0x3F800000u - ((b1 + 1u) << 16) + 1u);
    }
    __syncthreads();
    int t2 = t2s;
    for (int it = 0; it < 256; ++it){
      float4 v = hp[it*1024 + t];
      u32 idx0 = (u32)(it*1024 + t)*4u;
      #pragma unroll
      for (int c = 0; c < 4; ++c){
        float val = (c==0)?v.x:(c==1)?v.y:(c==2)?v.z:v.w;
        int bits = (int)__float_as_uint(val);   // signed cmp excludes negatives
        if (bits >= t2){
          u32 p = atomicAdd(&lc, 1u);
          if (p < CAP) cand[(size_t)s*CAP + p] = make_uint2((u32)bits, idx0 + (u32)c);
        }
      }
    }
    __syncthreads();
    n = (lc < CAP) ? lc : CAP;
    for (u32 i = t; i < n; i += 1024){
      uint2 cv = cand[(size_t)s*CAP + i];
      lkey[i] = ((u64)(~cv.x) << 32) | (u64)cv.y;
    }
    __syncthreads();
  }

  // ---- rank-by-count over this block's range: rank = #{key' < key} ----
  u32 lo = fb ? 0u : (u32)h * ((n + 1u) >> 1);
  u32 hi = fb ? n  : (h ? n : ((n + 1u) >> 1));
  const ulonglong2* lk2 = (const ulonglong2*)lkey;
  for (u32 me = lo + t; me < hi; me += 1024){
    u64 k0 = lkey[me];
    u32 r = 0;
    u32 half = n >> 1;
    for (u32 j = 0; j < half; ++j){
      ulonglong2 kk = lk2[j];               // LDS broadcast read
      r += (kk.x < k0) ? 1u : 0u;
      r += (kk.y < k0) ? 1u : 0u;
    }
    if (n & 1u) r += (lkey[n-1] < k0) ? 1u : 0u;
    if (r < 512u)
      sorted[s*512 + (int)r] = make_uint2(~(u32)(k0 >> 32), (u32)k0);
  }
}

// ---------------- KT: merge + decode + partition + greedy NMS (fused) --------
__global__ __launch_bounds__(1024) void kT_tail(const uint2* __restrict__ sorted,
                                                const float* __restrict__ reg,
                                                const float* __restrict__ rots,
                                                const float* __restrict__ rotc,
                                                const float* __restrict__ hei,
                                                const float* __restrict__ dim,
                                                const float* __restrict__ vel,
                                                float* out){
  __shared__ u64 k2a[512], k2b[512];
  __shared__ uint2 fin[512];           // .x=score bits, .y=idx | cls<<20
  __shared__ float xo[512], yo[512];
  __shared__ float2 pts[512];
  __shared__ int order[512], vld[512];
  __shared__ u32 ordvl[512];
  __shared__ int wsum[16];
  __shared__ u64 keepw[8];
  int b = blockIdx.x, t = threadIdx.x;

  // ---- phase 1: load both sorted lists, level-2 keys (score desc, concat-pos asc)
  uint2 mye = make_uint2(0u, 0u);
  if (t < 512){
    mye = sorted[(b*2 + 0)*512 + t];
    k2a[t] = ((u64)(~mye.x) << 32) | (u64)t;
  } else {
    int p = t - 512;
    mye = sorted[(b*2 + 1)*512 + p];
    k2b[p] = ((u64)(~mye.x) << 32) | (u64)(KTOP + p);
  }
  if (t < 8) keepw[t] = 0ull;
  __syncthreads();

  // ---- phase 2: merged rank = own rank + lower_bound in other list
  if (t < KTOP){
    u64 K = k2a[t];
    int lo = 0, hi = KTOP;
    while (lo < hi){ int mid = (lo + hi) >> 1; if (k2b[mid] < K) lo = mid + 1; else hi = mid; }
    int m = t + lo;
    if (m < KTOP){
      fin[m] = make_uint2(mye.x, mye.y & 0xFFFFFu);
      out[36000 + b*KTOP + m] = __uint_as_float(mye.x);
      out[40000 + b*KTOP + m] = 0.0f;
    }
  } else if (t >= 512 && t < 512 + KTOP){
    int p = t - 512;
    u64 K = k2b[p];
    int lo = 0, hi = KTOP;
    while (lo < hi){ int mid = (lo + hi) >> 1; if (k2a[mid] < K) lo = mid + 1; else hi = mid; }
    int m = p + lo;
    if (m < KTOP){
      fin[m] = make_uint2(mye.x, (mye.y & 0xFFFFFu) | (1u << 20));
      out[36000 + b*KTOP + m] = __uint_as_float(mye.x);
      out[40000 + b*KTOP + m] = 1.0f;
    }
  }
  __syncthreads();

  // ---- phase 3: gather + decode + valid
  float x = 0.f, y = 0.f; int v = 0;
  if (t < KTOP){
    uint2 e = fin[t];
    u32 ind = e.y & 0xFFFFFu;
    float mysc = __uint_as_float(e.x);
    float xs0 = (float)(ind & 1023u);
    float ys0 = (float)(ind >> 10);
    size_t bb = (size_t)b;
    float r0  = reg [(bb*2 + 0)*HW + ind];
    float r1  = reg [(bb*2 + 1)*HW + ind];
    float sn  = rots[ bb       *HW + ind];
    float cs  = rotc[ bb       *HW + ind];
    float he  = hei [ bb       *HW + ind];
    float d0  = dim [(bb*3 + 0)*HW + ind];
    float d1  = dim [(bb*3 + 1)*HW + ind];
    float d2v = dim [(bb*3 + 2)*HW + ind];
    float v0  = vel [(bb*2 + 0)*HW + ind];
    float v1  = vel [(bb*2 + 1)*HW + ind];
    x = xs0 + r0; y = ys0 + r1;
    float rot = atan2f(sn, cs);
    float* bx = out + (size_t)(b*KTOP + t)*9;
    bx[0]=x; bx[1]=y; bx[2]=he; bx[3]=d0; bx[4]=d1; bx[5]=d2v; bx[6]=rot; bx[7]=v0; bx[8]=v1;
    v = ((x >= -100.0f) && (x <= 1124.0f) &&
         (y >= -100.0f) && (y <= 1124.0f) &&
         (he >= -10.0f) && (he <= 10.0f) && (mysc > 0.1f)) ? 1 : 0;
    out[44000 + b*KTOP + t] = v ? 1.0f : 0.0f;
  }
  if (t < 512){ xo[t] = x; yo[t] = y; vld[t] = v; }

  // ---- phase 4: 1-barrier ballot scan, stable valid-first partition
  u64 bm = __ballot(v != 0);
  int lane = t & 63, wv = t >> 6;
  if (lane == 0) wsum[wv] = __popcll(bm);
  __syncthreads();
  int off = 0, nValid = 0;
  #pragma unroll
  for (int w2 = 0; w2 < 8; ++w2){
    int sv = wsum[w2];
    nValid += sv;
    if (w2 < wv) off += sv;
  }
  int incl = off + __popcll(bm & ((~0ull) >> (63 - lane)));
  if (t < KTOP){
    int excl = incl - v;
    int slot = v ? excl : (nValid + (t - excl));
    order[slot] = t;
  }
  __syncthreads();

  // ---- phase 5: ordered points + ordv into LDS
  if (t < KTOP){
    int p = order[t];
    pts[t] = make_float2(xo[p], yo[p]);
    ordvl[t] = (u32)p | ((u32)vld[p] << 31);
  } else if (t < 512){
    pts[t] = make_float2(1e30f, 1e30f);
    ordvl[t] = 0u;
  }
  __syncthreads();

  // ---- phase 6: greedy kept-set scan (wave 0 only; kept set in lane regs)
  if (t < 64){
    int nv = nValid;
    float kx0 = 1e30f, ky0 = 1e30f, kx1 = 1e30f, ky1 = 1e30f;
    int count = 0;
    u64 curw = 0ull;
    int i = 0;
    float2 pcur = pts[0];
    float2 pnxt = pts[1];
    for (i = 0; i < nv; ++i){
      float2 p = pcur;
      pcur = pnxt;
      pnxt = pts[(i + 2 < 512) ? (i + 2) : 511];   // prefetch 2 ahead
      float dx0 = __fsub_rn(kx0, p.x), dy0 = __fsub_rn(ky0, p.y);
      float dx1 = __fsub_rn(kx1, p.x), dy1 = __fsub_rn(ky1, p.y);
      float d20 = __fadd_rn(__fmul_rn(dx0,dx0), __fmul_rn(dy0,dy0));
      float d21 = __fadd_rn(__fmul_rn(dx1,dx1), __fmul_rn(dy1,dy1));
      bool nearby = (d20 <= 4.0f) || (d21 <= 4.0f);
      if (!__any(nearby)){
        // keep candidate i: append (uniform) point to lane #count's registers
        curw |= (1ull << (i & 63));
        if (count < 64){
          if (t == count){ kx0 = p.x; ky0 = p.y; }
        } else {
          if (t == count - 64){ kx1 = p.x; ky1 = p.y; }
        }
        ++count;
        if (count == POST_MAX) break;   // cap: later entries can never be kept
      }
      if ((i & 63) == 63){
        if (t == 0) keepw[i >> 6] |= curw;
        curw = 0ull;
      }
    }
    if (t == 0 && curw != 0ull){
      int wi = i >> 6; if (wi > 7) wi = 7;
      keepw[wi] |= curw;
    }
  }
  __syncthreads();

  // ---- phase 7: keep-write
  if (t < KTOP){
    int bit = (int)((keepw[t >> 6] >> (t & 63)) & 1ull);
    u32 pv = ordvl[t];
    int p = (int)(pv & 511u);
    out[48000 + b*KTOP + p] = (bit && (pv >> 31)) ? 1.0f : 0.0f;
  }
}

extern "C" void kernel_launch(void* const* d_in, const int* in_sizes, int n_in,
                              void* d_out, int out_size, void* d_ws, size_t ws_size,
                              hipStream_t stream){
  const float* heat = (const float*)d_in[0];
  const float* reg  = (const float*)d_in[1];
  const float* rots = (const float*)d_in[2];
  const float* rotc = (const float*)d_in[3];
  const float* hei  = (const float*)d_in[4];
  const float* dim  = (const float*)d_in[5];
  const float* vel  = (const float*)d_in[6];
  float* out = (float*)d_out;
  char* ws = (char*)d_ws;
  u32*   cnt2   = (u32*)  (ws + WS_CNT2);
  uint2* cand   = (uint2*)(ws + WS_CAND);
  uint2* sorted = (uint2*)(ws + WS_SORT);

  k1_collect <<<2048, 256, 0, stream>>>(heat, cnt2, cand);
  kR_rank    <<<32,  1024, 0, stream>>>(heat, cnt2, cand, sorted);
  kT_tail    <<<8,   1024, 0, stream>>>(sorted, reg, rots, rotc, hei, dim, vel, out);
}